// Round 4
// baseline (193.145 us; speedup 1.0000x reference)
//
#include <hip/hip_runtime.h>

#define FN   128    // nodes per graph
#define HDIM 128    // hidden dim
#define NH   4      // heads, layer 0
#define HSZ  32     // head dim, layer 0
#define EB   1024   // base edges per graph
#define ET   1152   // edges incl. self loops
#define RSW  132    // padded LDS row stride (words)

typedef __attribute__((ext_vector_type(8))) short bf16x8;
typedef __attribute__((ext_vector_type(4))) float f32x4;
typedef unsigned int u32;
typedef unsigned short u16;

union U8 { bf16x8 v; u32 u[4]; };

__device__ __forceinline__ u32 pack_hl(float v) {
  const u32 u = __float_as_uint(v);
  const u32 hib = u & 0xFFFF0000u;
  const float lo = v - __uint_as_float(hib);
  return hib | (__float_as_uint(lo) >> 16);
}
__device__ __forceinline__ float lrelu(float v) {
  return (v > 0.f) ? v : 0.2f * v;
}

__device__ __forceinline__ void unpack_frag(const u32* __restrict__ q,
                                            bf16x8& hi, bf16x8& lo)
{
  const uint4 p0 = *(const uint4*)(q);
  const uint4 p1 = *(const uint4*)(q + 4);
  U8 H, L;
  H.u[0] = (p0.x >> 16) | (p0.y & 0xFFFF0000u);
  L.u[0] = (p0.x & 0xFFFFu) | (p0.y << 16);
  H.u[1] = (p0.z >> 16) | (p0.w & 0xFFFF0000u);
  L.u[1] = (p0.z & 0xFFFFu) | (p0.w << 16);
  H.u[2] = (p1.x >> 16) | (p1.y & 0xFFFF0000u);
  L.u[2] = (p1.x & 0xFFFFu) | (p1.y << 16);
  H.u[3] = (p1.z >> 16) | (p1.w & 0xFFFF0000u);
  L.u[3] = (p1.z & 0xFFFFu) | (p1.w << 16);
  hi = H.v; lo = L.v;
}

// ---------------- prep: blocks 0..127 = W split; block 128 = shared CSR ----
// csr layout: src u16[1152] | int rp[129] | int perm[128]
// Per-node edge lists are sorted by (src - n) & 7 so that the fused gather's
// 64 concurrent lanes (holding 64 distinct nodes n) read rows stratified
// across all 8 LDS bank groups (row stride 132 == 4 mod 32 -> 8 groups).
__global__ __launch_bounds__(256) void prep_kernel(
    const float* __restrict__ g0w, const float* __restrict__ g1w,
    const int* __restrict__ ei,
    u16* __restrict__ wf, u16* __restrict__ csrS, int* __restrict__ csrI)
{
  if (blockIdx.x == 128) {               // -------- CSR build (topology shared)
    __shared__ int deg[FN], rp[FN + 1], fill[FN];
    __shared__ u16 eb[ET];
    const int t = threadIdx.x;
    if (t < FN) { deg[t] = 0; fill[t] = 0; }
    __syncthreads();
    for (int e = t; e < EB; e += 256) atomicAdd(&deg[ei[EB + e]], 1);
    __syncthreads();
    if (t < 64) {                        // wave-0 exclusive scan of (deg+1)
      const int v0 = deg[2 * t] + 1, v1 = deg[2 * t + 1] + 1;
      const int p = v0 + v1;
      int sc = p;
      #pragma unroll
      for (int off = 1; off < 64; off <<= 1) {
        const int o = __shfl_up(sc, off, 64);
        if (t >= off) sc += o;
      }
      rp[2 * t] = sc - p;
      rp[2 * t + 1] = sc - v1;
      if (t == 63) rp[128] = sc;         // == ET
    }
    __syncthreads();
    if (t < FN) {
      // rank by (degree desc, node id) -> perm[rank] = node; bijective
      const int dn = deg[t];
      int rk = 0;
      for (int m = 0; m < FN; ++m) {
        const int dm = deg[m];
        rk += (dm > dn) || (dm == dn && m < t);
      }
      csrI[129 + rk] = t;                // perm
      csrI[t] = rp[t];                   // rp
      if (t == 0) csrI[FN] = rp[FN];
    }
    __syncthreads();
    for (int e = t; e < EB; e += 256) {
      const int d = ei[EB + e], s = ei[e];
      const int p = rp[d] + atomicAdd(&fill[d], 1);
      eb[p] = (u16)s;
    }
    if (t < FN) eb[rp[t] + deg[t]] = (u16)t;     // self loop in last slot
    __syncthreads();
    if (t < FN) {                        // per-node insertion sort by bank key
      const int e0 = rp[t], e1 = rp[t] + deg[t] + 1;
      for (int i = e0 + 1; i < e1; ++i) {
        const u16 v = eb[i];
        const int kv = ((int)v - t) & 7;
        int j = i - 1;
        while (j >= e0 && (((int)eb[j] - t) & 7) > kv) { eb[j + 1] = eb[j]; --j; }
        eb[j + 1] = v;
      }
    }
    __syncthreads();
    for (int e = t; e < ET; e += 256) csrS[e] = eb[e];
    return;
  }

  // -------- W -> split bf16 hi/lo, B-fragment layout (r3-verified)
  const int idx = blockIdx.x * 256 + threadIdx.x;   // 32768 total
  const int layer = idx >> 14;
  const int r = idx & 16383;
  const int c  = r >> 11;
  const int kc = (r >> 9) & 3;
  const int l  = (r >> 3) & 63;
  const int j  = r & 7;
  const int k = kc * 32 + (l >> 4) * 8 + j;
  const int n = c * 16 + (l & 15);
  const float* W = layer ? g1w : g0w;
  const float v = W[k * HDIM + n];
  const u32 u = __float_as_uint(v);
  const u32 hib = u & 0xFFFF0000u;
  const float lo = v - __uint_as_float(hib);
  wf[layer * 32768 + r]         = (u16)(u >> 16);
  wf[layer * 32768 + 16384 + r] = (u16)(__float_as_uint(lo) >> 16);
}

// MFMA GEMM, 8 waves/graph (r12/r14-verified): wave tile 32 cols x 64 rows.
__device__ __forceinline__ void mfma_gemm_acc(const u32* __restrict__ F,
                                              const u16* __restrict__ wf,
                                              int lw, int lane, f32x4 acc[4][2])
{
  const int cg = lw & 3, rh = lw >> 2;
  const int m = lane & 15, quad = lane >> 4;

  #pragma unroll
  for (int s = 0; s < 4; ++s)
    #pragma unroll
    for (int ct = 0; ct < 2; ++ct) acc[s][ct] = (f32x4){0.f, 0.f, 0.f, 0.f};

  const u16* bbase = wf + (cg * 8) * 512 + lane * 8;   // ct +2048, kc +512

  #pragma unroll
  for (int kc = 0; kc < 4; ++kc) {
    bf16x8 bhi[2], blo[2];
    #pragma unroll
    for (int ct = 0; ct < 2; ++ct) {
      const u16* bp = bbase + ct * 2048 + kc * 512;
      bhi[ct] = *(const bf16x8*)bp;
      blo[ct] = *(const bf16x8*)(bp + 16384);
    }
    #pragma unroll
    for (int s = 0; s < 4; ++s) {
      const u32* ap = F + (rh * 64 + s * 16 + m) * RSW + quad * 8 + kc * 32;
      bf16x8 ahi, alo;
      unpack_frag(ap, ahi, alo);
      #pragma unroll
      for (int ct = 0; ct < 2; ++ct) {
        acc[s][ct] = __builtin_amdgcn_mfma_f32_16x16x32_bf16(ahi, bhi[ct], acc[s][ct], 0, 0, 0);
        acc[s][ct] = __builtin_amdgcn_mfma_f32_16x16x32_bf16(alo, bhi[ct], acc[s][ct], 0, 0, 0);
        acc[s][ct] = __builtin_amdgcn_mfma_f32_16x16x32_bf16(ahi, blo[ct], acc[s][ct], 0, 0, 0);
      }
    }
  }
}

// store acc -> plain f32 (in-place into F); C/D: col = lane&15, row = quad*4+r
__device__ __forceinline__ void store_acc(float* __restrict__ sg, int lw,
                                          int lane, const f32x4 acc[4][2])
{
  const int cg = lw & 3, rh = lw >> 2;
  const int m = lane & 15, quad = lane >> 4;
  #pragma unroll
  for (int s = 0; s < 4; ++s) {
    const int row0 = rh * 64 + s * 16 + quad * 4;
    #pragma unroll
    for (int ct = 0; ct < 2; ++ct)
      #pragma unroll
      for (int r = 0; r < 4; ++r)
        sg[(row0 + r) * RSW + cg * 32 + ct * 16 + m] = acc[s][ct][r];
  }
}

// ---------------- fused GNN: 512 threads, ONE graph per block --------------
// ~76.3 KB LDS -> two blocks co-resident per CU.
__global__ __launch_bounds__(512, 4) void gnn_fused_kernel(
    const float* __restrict__ x,
    const float* __restrict__ w_in, const float* __restrict__ b_in,
    const float* __restrict__ g0as, const float* __restrict__ g0ad,
    const float* __restrict__ g0b,
    const float* __restrict__ bn0g, const float* __restrict__ bn0b,
    const float* __restrict__ bn0m, const float* __restrict__ bn0v,
    const float* __restrict__ g1as, const float* __restrict__ g1ad,
    const float* __restrict__ g1b,
    const float* __restrict__ bn1g, const float* __restrict__ bn1b,
    const float* __restrict__ bn1m, const float* __restrict__ bn1v,
    const float* __restrict__ w1, const float* __restrict__ b1,
    const float* __restrict__ w2, const float* __restrict__ b2,
    const u16* __restrict__ wf, const u16* __restrict__ csrS,
    const int* __restrict__ csrI,
    float* __restrict__ out)
{
  __shared__ u32   F[FN * RSW];        // 67584 B: packed feat <-> f32 sg
  __shared__ int   s_rp[FN + 1];
  __shared__ int   s_perm[FN];         // degree-sorted node order
  __shared__ u16   s_src[ET];          // src node per edge (2304 B)
  __shared__ float s_scr[1280];        // es 512 | ed 512 | rs 256
  __shared__ float s_bn[512];          // folded BN consts

  const int t = threadIdx.x;
  const int gid = blockIdx.x;          // graph id
  const int lane = t & 63;
  const int lw = t >> 6;               // wave 0..7
  float* s_es = s_scr;
  float* s_ed = s_scr + 512;
  float* s_rs = s_scr + 1024;
  f32x4 acc[4][2];

  // ================= prologue: CSR load + BN fold + input projection =======
  for (int w = t; w < ET / 2; w += 512)            // 576 u32 words (ALL 1152)
    ((u32*)s_src)[w] = ((const u32*)csrS)[w];
  if (t < FN + 1) s_rp[t] = csrI[t];
  if (t < FN)     s_perm[t] = csrI[129 + t];
  if (t >= 256 && t < 512) {           // fold BN consts (other waves)
    const int layer = (t >> 7) & 1;
    const int col = t & 127;
    const float bb = layer ? g1b[col]  : g0b[col];
    const float bm = layer ? bn1m[col] : bn0m[col];
    const float bv = layer ? bn1v[col] : bn0v[col];
    const float bg = layer ? bn1g[col] : bn0g[col];
    const float bt = layer ? bn1b[col] : bn0b[col];
    const float q = bg * rsqrtf(bv + 1e-5f);
    s_bn[layer * 256 + col] = q;
    s_bn[layer * 256 + 128 + col] = (bb - bm) * q + bt;
  }
  {                                    // input projection + ReLU -> F packed
    const int j = t & 127, q = t >> 7;
    const float wv = w_in[j], bv = b_in[j];
    const size_t xb = (size_t)gid * FN;
    for (int n = q * 32; n < q * 32 + 32; ++n) {
      const float v = fmaxf(fmaf(x[xb + n], wv, bv), 0.f);
      F[n * RSW + j] = pack_hl(v);
    }
  }
  __syncthreads();

  // ======================= GAT layer 0 =======================
  mfma_gemm_acc(F, wf, lw, lane, acc);
  __syncthreads();                       // all packed reads done
  store_acc((float*)F, lw, lane, acc);   // F now f32 sg
  __syncthreads();

  // logits per (head, node)
  {
    const int hh = t >> 7, n = t & 127;
    const float* row = (const float*)F + n * RSW + hh * HSZ;
    float accs = 0.f, accd = 0.f;
    #pragma unroll
    for (int s = 0; s < 8; ++s) {
      const int d = ((n + s) & 7) * 4;
      const float4 v  = *(const float4*)(row + d);
      const float4 as = *(const float4*)(g0as + hh * HSZ + d);
      const float4 ad = *(const float4*)(g0ad + hh * HSZ + d);
      accs += v.x*as.x + v.y*as.y + v.z*as.z + v.w*as.w;
      accd += v.x*ad.x + v.y*ad.y + v.z*ad.z + v.w*ad.w;
    }
    s_es[hh * 128 + n] = accs;
    s_ed[hh * 128 + n] = accd;
  }
  __syncthreads();

  // ---- aggregation: thread = (sorted-node, head); single merged pass
  //      (edge lists bank-stratified by prep sort)
  {
    const int slot = t & 127, hh = t >> 7;
    const int n = s_perm[slot];          // degree-balanced within wave
    const int cb = hh * HSZ;
    const float* Ff = (const float*)F;
    const int e0 = s_rp[n], e1 = s_rp[n + 1];
    const float edv = s_ed[hh * 128 + n];
    const float* esb = s_es + hh * 128;
    float sum = 0.f;
    float4 a[8];
    #pragma unroll
    for (int i = 0; i < 8; ++i) a[i] = make_float4(0.f, 0.f, 0.f, 0.f);
    for (int e = e0; e < e1; ++e) {
      const int s = s_src[e];
      const float al = __expf(lrelu(esb[s] + edv));
      sum += al;
      const float* rp_ = Ff + s * RSW + cb;
      #pragma unroll
      for (int i = 0; i < 8; ++i) {
        const float4 vv = *(const float4*)(rp_ + i * 4);
        a[i].x = fmaf(al, vv.x, a[i].x); a[i].y = fmaf(al, vv.y, a[i].y);
        a[i].z = fmaf(al, vv.z, a[i].z); a[i].w = fmaf(al, vv.w, a[i].w);
      }
    }
    const float rsv = 1.f / sum;
    __syncthreads();                     // all sg reads done -> overwrite F
    #pragma unroll
    for (int i = 0; i < 8; ++i) {
      const int col = cb + i * 4;
      const float4 q = *(const float4*)&s_bn[col];
      const float4 r = *(const float4*)&s_bn[128 + col];
      uint4 p;
      p.x = pack_hl(fmaxf(fmaf(a[i].x * rsv, q.x, r.x), 0.f));
      p.y = pack_hl(fmaxf(fmaf(a[i].y * rsv, q.y, r.y), 0.f));
      p.z = pack_hl(fmaxf(fmaf(a[i].z * rsv, q.z, r.z), 0.f));
      p.w = pack_hl(fmaxf(fmaf(a[i].w * rsv, q.w, r.w), 0.f));
      *(uint4*)(F + n * RSW + col) = p;
    }
  }
  __syncthreads();

  // ======================= GAT layer 1 (1 head) =======================
  mfma_gemm_acc(F, wf + 32768, lw, lane, acc);
  __syncthreads();
  store_acc((float*)F, lw, lane, acc);
  __syncthreads();

  // logits partials: 512 threads -> 4 partials per node
  {
    const int n = t >> 2, c = t & 3;
    const float* row = (const float*)F + n * RSW + c * 32;
    float accs = 0.f, accd = 0.f;
    #pragma unroll
    for (int i = 0; i < 8; ++i) {
      const int d = i * 4;
      const float4 v  = *(const float4*)(row + d);
      const float4 as = *(const float4*)(g1as + c * 32 + d);
      const float4 ad = *(const float4*)(g1ad + c * 32 + d);
      accs += v.x*as.x + v.y*as.y + v.z*as.z + v.w*as.w;
      accd += v.x*ad.x + v.y*ad.y + v.z*ad.z + v.w*ad.w;
    }
    s_es[t] = accs;                      // partials [n*4+c]
    s_ed[t] = accd;
  }
  __syncthreads();
  if (t < 128) {                         // combine -> s_rs[n]=es, s_rs[128+n]=ed
    const float* pe = s_es + t * 4;
    const float* pd = s_ed + t * 4;
    s_rs[t]       = pe[0] + pe[1] + pe[2] + pe[3];
    s_rs[128 + t] = pd[0] + pd[1] + pd[2] + pd[3];
  }
  __syncthreads();

  // aggregation layer 1: thread = (sorted-node, col-quarter); merged pass;
  // epilogue stores RAW f32 (pool is the only consumer)
  {
    const int slot = t & 127, cg = t >> 7;
    const int cb = cg * HSZ;
    const int n = s_perm[slot];
    const float* Ff = (const float*)F;
    const int e0 = s_rp[n], e1 = s_rp[n + 1];
    const float edv = s_rs[128 + n];
    float sum = 0.f;
    float4 a[8];
    #pragma unroll
    for (int i = 0; i < 8; ++i) a[i] = make_float4(0.f, 0.f, 0.f, 0.f);
    for (int e = e0; e < e1; ++e) {
      const int s = s_src[e];
      const float al = __expf(lrelu(s_rs[s] + edv));
      sum += al;
      const float* rp_ = Ff + s * RSW + cb;
      #pragma unroll
      for (int i = 0; i < 8; ++i) {
        const float4 vv = *(const float4*)(rp_ + i * 4);
        a[i].x = fmaf(al, vv.x, a[i].x); a[i].y = fmaf(al, vv.y, a[i].y);
        a[i].z = fmaf(al, vv.z, a[i].z); a[i].w = fmaf(al, vv.w, a[i].w);
      }
    }
    const float rsv = 1.f / sum;
    __syncthreads();                     // all sg reads done -> overwrite F
    #pragma unroll
    for (int i = 0; i < 8; ++i) {
      const int col = cb + i * 4;
      const float4 q = *(const float4*)&s_bn[256 + col];
      const float4 r = *(const float4*)&s_bn[384 + col];
      uint4 p;
      p.x = __float_as_uint(fmaxf(fmaf(a[i].x * rsv, q.x, r.x), 0.f));
      p.y = __float_as_uint(fmaxf(fmaf(a[i].y * rsv, q.y, r.y), 0.f));
      p.z = __float_as_uint(fmaxf(fmaf(a[i].z * rsv, q.z, r.z), 0.f));
      p.w = __float_as_uint(fmaxf(fmaf(a[i].w * rsv, q.w, r.w), 0.f));
      *(uint4*)(F + n * RSW + col) = p;
    }
  }
  __syncthreads();

  // ---- mean pool (raw f32 in F) + MLP head
  {
    const int j = t & 127, q = t >> 7;
    float p = 0.f;
    for (int n = q * 32; n < q * 32 + 32; ++n)
      p += __uint_as_float(F[n * RSW + j]);
    s_es[q * 128 + j] = p;
  }
  __syncthreads();
  if (t < 128) {
    s_ed[t] = (s_es[t] + s_es[t + 128] + s_es[t + 256] + s_es[t + 384])
              * (1.f / 128.f);
  }
  __syncthreads();
  {
    const int j = t & 63, part = t >> 6;
    float a = 0.f;
    #pragma unroll
    for (int k = part * 16; k < part * 16 + 16; ++k)
      a = fmaf(s_ed[k], w1[k * 64 + j], a);
    s_es[part * 64 + j] = a;
  }
  __syncthreads();
  if (t < 64) {
    float a = b1[t];
    #pragma unroll
    for (int p = 0; p < 8; ++p) a += s_es[p * 64 + t];
    a = fmaxf(a, 0.f);
    float v = a * w2[t];
    #pragma unroll
    for (int off = 32; off > 0; off >>= 1) v += __shfl_down(v, off, 64);
    if (t == 0) out[gid] = v + b2[0];
  }
}

extern "C" void kernel_launch(void* const* d_in, const int* in_sizes, int n_in,
                              void* d_out, int out_size, void* d_ws, size_t ws_size,
                              hipStream_t stream)
{
  const float* x    = (const float*)d_in[0];
  const int*   ei   = (const int*)d_in[1];
  const float* w_in = (const float*)d_in[2];
  const float* b_in = (const float*)d_in[3];
  const float* g0w  = (const float*)d_in[4];
  const float* g0as = (const float*)d_in[5];
  const float* g0ad = (const float*)d_in[6];
  const float* g0b  = (const float*)d_in[7];
  const float* bn0g = (const float*)d_in[8];
  const float* bn0b = (const float*)d_in[9];
  const float* bn0m = (const float*)d_in[10];
  const float* bn0v = (const float*)d_in[11];
  const float* g1w  = (const float*)d_in[12];
  const float* g1as = (const float*)d_in[13];
  const float* g1ad = (const float*)d_in[14];
  const float* g1b  = (const float*)d_in[15];
  const float* bn1g = (const float*)d_in[16];
  const float* bn1b = (const float*)d_in[17];
  const float* bn1m = (const float*)d_in[18];
  const float* bn1v = (const float*)d_in[19];
  const float* w1   = (const float*)d_in[20];
  const float* b1   = (const float*)d_in[21];
  const float* w2   = (const float*)d_in[22];
  const float* b2   = (const float*)d_in[23];

  u16* wf   = (u16*)d_ws;                          // 128 KB
  u16* csrS = (u16*)((char*)d_ws + 131072);        // 1152 u16 = 2304 B
  int* csrI = (int*)((char*)d_ws + 131072 + 2304); // rp[129] | perm[128]

  prep_kernel<<<129, 256, 0, stream>>>(g0w, g1w, ei, wf, csrS, csrI);
  gnn_fused_kernel<<<1024, 512, 0, stream>>>(x, w_in, b_in,
      g0as, g0ad, g0b, bn0g, bn0b, bn0m, bn0v,
      g1as, g1ad, g1b, bn1g, bn1b, bn1m, bn1v,
      w1, b1, w2, b2, wf, csrS, csrI, (float*)d_out);
}

// Round 5
// 173.273 us; speedup vs baseline: 1.1147x; 1.1147x over previous
//
#include <hip/hip_runtime.h>

#define FN   128    // nodes per graph
#define HDIM 128    // hidden dim
#define NH   4      // heads, layer 0
#define HSZ  32     // head dim, layer 0
#define EB   1024   // base edges per graph
#define ET   1152   // edges incl. self loops
#define RSW  132    // padded f32 scratch row stride (words)
#define RSP  68     // plane row stride (words of bf16-pairs), 272 B = 17*16
#define PLO  (FN * RSP)   // lo-plane offset (words)

typedef __attribute__((ext_vector_type(8))) short bf16x8;
typedef __attribute__((ext_vector_type(4))) float f32x4;
typedef unsigned int u32;
typedef unsigned short u16;

__device__ __forceinline__ float lrelu(float v) {
  return (v > 0.f) ? v : 0.2f * v;
}

// split two f32 into (hi-pair word, lo-pair word); low half = first value.
// Same truncating hi/lo scheme as the r3-verified W split.
__device__ __forceinline__ void split_pair(float v0, float v1,
                                           u32& hw, u32& lw_)
{
  const u32 u0 = __float_as_uint(v0), u1 = __float_as_uint(v1);
  const u32 h0 = u0 & 0xFFFF0000u,  h1 = u1 & 0xFFFF0000u;
  const float l0 = v0 - __uint_as_float(h0);
  const float l1 = v1 - __uint_as_float(h1);
  hw  = (h0 >> 16) | h1;
  lw_ = (__float_as_uint(l0) >> 16) | (__float_as_uint(l1) & 0xFFFF0000u);
}

// ---------------- prep: blocks 0..127 = W split; block 128 = shared CSR ----
// csr layout: src u16[1152] | int rp[129] | int perm[128]
__global__ __launch_bounds__(256) void prep_kernel(
    const float* __restrict__ g0w, const float* __restrict__ g1w,
    const int* __restrict__ ei,
    u16* __restrict__ wf, u16* __restrict__ csrS, int* __restrict__ csrI)
{
  if (blockIdx.x == 128) {               // -------- CSR build (topology shared)
    __shared__ int deg[FN], rp[FN + 1], fill[FN];
    const int t = threadIdx.x;
    if (t < FN) { deg[t] = 0; fill[t] = 0; }
    __syncthreads();
    for (int e = t; e < EB; e += 256) atomicAdd(&deg[ei[EB + e]], 1);
    __syncthreads();
    if (t < 64) {                        // wave-0 exclusive scan of (deg+1)
      const int v0 = deg[2 * t] + 1, v1 = deg[2 * t + 1] + 1;
      const int p = v0 + v1;
      int sc = p;
      #pragma unroll
      for (int off = 1; off < 64; off <<= 1) {
        const int o = __shfl_up(sc, off, 64);
        if (t >= off) sc += o;
      }
      rp[2 * t] = sc - p;
      rp[2 * t + 1] = sc - v1;
      if (t == 63) rp[128] = sc;         // == ET
    }
    __syncthreads();
    if (t < FN) {
      // rank by (degree desc, node id) -> perm[rank] = node; bijective
      const int dn = deg[t];
      int rk = 0;
      for (int m = 0; m < FN; ++m) {
        const int dm = deg[m];
        rk += (dm > dn) || (dm == dn && m < t);
      }
      csrI[129 + rk] = t;                // perm
      csrI[t] = rp[t];                   // rp
      if (t == 0) csrI[FN] = rp[FN];
    }
    __syncthreads();
    for (int e = t; e < EB; e += 256) {
      const int d = ei[EB + e], s = ei[e];
      const int p = rp[d] + atomicAdd(&fill[d], 1);
      csrS[p] = (u16)s;                  // only src needed by gather
    }
    if (t < FN) csrS[rp[t] + deg[t]] = (u16)t;   // self loop in last slot
    return;
  }

  // -------- W -> split bf16 hi/lo, B-fragment layout (r3-verified)
  const int idx = blockIdx.x * 256 + threadIdx.x;   // 32768 total
  const int layer = idx >> 14;
  const int r = idx & 16383;
  const int c  = r >> 11;
  const int kc = (r >> 9) & 3;
  const int l  = (r >> 3) & 63;
  const int j  = r & 7;
  const int k = kc * 32 + (l >> 4) * 8 + j;
  const int n = c * 16 + (l & 15);
  const float* W = layer ? g1w : g0w;
  const float v = W[k * HDIM + n];
  const u32 u = __float_as_uint(v);
  const u32 hib = u & 0xFFFF0000u;
  const float lo = v - __uint_as_float(hib);
  wf[layer * 32768 + r]         = (u16)(u >> 16);
  wf[layer * 32768 + 16384 + r] = (u16)(__float_as_uint(lo) >> 16);
}

// MFMA GEMM, 8 waves/graph: wave tile 32 cols x 64 rows. A-fragments are
// read directly from the split hi/lo planes (no in-loop unpack VALU).
__device__ __forceinline__ void mfma_gemm_acc(const u32* __restrict__ F,
                                              const u16* __restrict__ wf,
                                              int lw, int lane, f32x4 acc[4][2])
{
  const int cg = lw & 3, rh = lw >> 2;
  const int m = lane & 15, quad = lane >> 4;

  #pragma unroll
  for (int s = 0; s < 4; ++s)
    #pragma unroll
    for (int ct = 0; ct < 2; ++ct) acc[s][ct] = (f32x4){0.f, 0.f, 0.f, 0.f};

  const u16* bbase = wf + (cg * 8) * 512 + lane * 8;   // ct +2048, kc +512

  #pragma unroll
  for (int kc = 0; kc < 4; ++kc) {
    bf16x8 bhi[2], blo[2];
    #pragma unroll
    for (int ct = 0; ct < 2; ++ct) {
      const u16* bp = bbase + ct * 2048 + kc * 512;
      bhi[ct] = *(const bf16x8*)bp;
      blo[ct] = *(const bf16x8*)(bp + 16384);
    }
    #pragma unroll
    for (int s = 0; s < 4; ++s) {
      const u32* ap = F + (rh * 64 + s * 16 + m) * RSP + quad * 4 + kc * 16;
      const bf16x8 ahi = *(const bf16x8*)ap;
      const bf16x8 alo = *(const bf16x8*)(ap + PLO);
      #pragma unroll
      for (int ct = 0; ct < 2; ++ct) {
        acc[s][ct] = __builtin_amdgcn_mfma_f32_16x16x32_bf16(ahi, bhi[ct], acc[s][ct], 0, 0, 0);
        acc[s][ct] = __builtin_amdgcn_mfma_f32_16x16x32_bf16(alo, bhi[ct], acc[s][ct], 0, 0, 0);
        acc[s][ct] = __builtin_amdgcn_mfma_f32_16x16x32_bf16(ahi, blo[ct], acc[s][ct], 0, 0, 0);
      }
    }
  }
}

// store acc -> plain f32 scratch (stride RSW); C/D: col = lane&15, row = quad*4+r
__device__ __forceinline__ void store_acc(float* __restrict__ sg, int lw,
                                          int lane, const f32x4 acc[4][2])
{
  const int cg = lw & 3, rh = lw >> 2;
  const int m = lane & 15, quad = lane >> 4;
  #pragma unroll
  for (int s = 0; s < 4; ++s) {
    const int row0 = rh * 64 + s * 16 + quad * 4;
    #pragma unroll
    for (int ct = 0; ct < 2; ++ct)
      #pragma unroll
      for (int r = 0; r < 4; ++r)
        sg[(row0 + r) * RSW + cg * 32 + ct * 16 + m] = acc[s][ct][r];
  }
}

// ---------------- fused GNN: 512 threads, ONE graph per block --------------
// ~80.2 KB LDS -> two blocks co-resident per CU.
__global__ __launch_bounds__(512, 4) void gnn_fused_kernel(
    const float* __restrict__ x,
    const float* __restrict__ w_in, const float* __restrict__ b_in,
    const float* __restrict__ g0as, const float* __restrict__ g0ad,
    const float* __restrict__ g0b,
    const float* __restrict__ bn0g, const float* __restrict__ bn0b,
    const float* __restrict__ bn0m, const float* __restrict__ bn0v,
    const float* __restrict__ g1as, const float* __restrict__ g1ad,
    const float* __restrict__ g1b,
    const float* __restrict__ bn1g, const float* __restrict__ bn1b,
    const float* __restrict__ bn1m, const float* __restrict__ bn1v,
    const float* __restrict__ w1, const float* __restrict__ b1,
    const float* __restrict__ w2, const float* __restrict__ b2,
    const u16* __restrict__ wf, const u16* __restrict__ csrS,
    const int* __restrict__ csrI,
    float* __restrict__ out)
{
  // F serves two views: split bf16 planes (2 x 128 x RSP) for GEMM input,
  // and f32 scratch rows (stride RSW, max idx 16895 < 17408) for outputs.
  __shared__ __align__(16) u32 F[2 * FN * RSP];   // 69632 B
  __shared__ int   s_rp[FN + 1];
  __shared__ int   s_perm[FN];         // degree-sorted node order
  __shared__ u16   s_src[ET];          // src node per edge (2304 B)
  __shared__ float s_scr[1280];        // es 512 | ed 512 | rs 256
  __shared__ float s_bn[512];          // folded BN consts

  const int t = threadIdx.x;
  const int gid = blockIdx.x;          // graph id
  const int lane = t & 63;
  const int lw = t >> 6;               // wave 0..7
  float* s_es = s_scr;
  float* s_ed = s_scr + 512;
  float* s_rs = s_scr + 1024;
  f32x4 acc[4][2];

  // ================= prologue: CSR load + BN fold + input projection =======
  for (int w = t; w < ET / 2; w += 512)            // 576 u32 words (ALL 1152)
    ((u32*)s_src)[w] = ((const u32*)csrS)[w];
  if (t < FN + 1) s_rp[t] = csrI[t];
  if (t < FN)     s_perm[t] = csrI[129 + t];
  if (t >= 256 && t < 512) {           // fold BN consts (other waves)
    const int layer = (t >> 7) & 1;
    const int col = t & 127;
    const float bb = layer ? g1b[col]  : g0b[col];
    const float bm = layer ? bn1m[col] : bn0m[col];
    const float bv = layer ? bn1v[col] : bn0v[col];
    const float bg = layer ? bn1g[col] : bn0g[col];
    const float bt = layer ? bn1b[col] : bn0b[col];
    const float q = bg * rsqrtf(bv + 1e-5f);
    s_bn[layer * 256 + col] = q;
    s_bn[layer * 256 + 128 + col] = (bb - bm) * q + bt;
  }
  {                                    // input projection + ReLU -> planes
    const int j2 = t & 63, q = t >> 6; // col pair (2j2, 2j2+1), 16 rows
    const int c0 = 2 * j2, c1 = c0 + 1;
    const float w0 = w_in[c0], b0 = b_in[c0];
    const float w1v = w_in[c1], b1v = b_in[c1];
    const size_t xb = (size_t)gid * FN;
    for (int n = q * 16; n < q * 16 + 16; ++n) {
      const float xv = x[xb + n];
      const float v0 = fmaxf(fmaf(xv, w0, b0), 0.f);
      const float v1 = fmaxf(fmaf(xv, w1v, b1v), 0.f);
      u32 hw, lw_;
      split_pair(v0, v1, hw, lw_);
      F[n * RSP + j2]       = hw;
      F[PLO + n * RSP + j2] = lw_;
    }
  }
  __syncthreads();

  // ======================= GAT layer 0 =======================
  mfma_gemm_acc(F, wf, lw, lane, acc);
  __syncthreads();                       // all plane reads done
  store_acc((float*)F, lw, lane, acc);   // F now f32 scratch
  __syncthreads();

  // logits per (head, node); skew (s + n>>3) spreads lanes over 8 bank quads
  {
    const int hh = t >> 7, n = t & 127;
    const float* row = (const float*)F + n * RSW + hh * HSZ;
    float accs = 0.f, accd = 0.f;
    #pragma unroll
    for (int s = 0; s < 8; ++s) {
      const int d = ((s + (n >> 3)) & 7) * 4;
      const float4 v  = *(const float4*)(row + d);
      const float4 as = *(const float4*)(g0as + hh * HSZ + d);
      const float4 ad = *(const float4*)(g0ad + hh * HSZ + d);
      accs += v.x*as.x + v.y*as.y + v.z*as.z + v.w*as.w;
      accd += v.x*ad.x + v.y*ad.y + v.z*ad.z + v.w*ad.w;
    }
    s_es[hh * 128 + n] = accs;
    s_ed[hh * 128 + n] = accd;
  }
  __syncthreads();

  // ---- aggregation: thread = (sorted-node, head); single merged pass
  {
    const int slot = t & 127, hh = t >> 7;
    const int n = s_perm[slot];          // degree-balanced within wave
    const int cb = hh * HSZ;
    const float* Ff = (const float*)F;
    const int e0 = s_rp[n], e1 = s_rp[n + 1];
    const float edv = s_ed[hh * 128 + n];
    const float* esb = s_es + hh * 128;
    float sum = 0.f;
    float4 a[8];
    #pragma unroll
    for (int i = 0; i < 8; ++i) a[i] = make_float4(0.f, 0.f, 0.f, 0.f);
    for (int e = e0; e < e1; ++e) {
      const int s = s_src[e];
      const float al = __expf(lrelu(esb[s] + edv));
      sum += al;
      const float* rp_ = Ff + s * RSW + cb;
      #pragma unroll
      for (int i = 0; i < 8; ++i) {
        const float4 vv = *(const float4*)(rp_ + i * 4);
        a[i].x = fmaf(al, vv.x, a[i].x); a[i].y = fmaf(al, vv.y, a[i].y);
        a[i].z = fmaf(al, vv.z, a[i].z); a[i].w = fmaf(al, vv.w, a[i].w);
      }
    }
    const float rsv = 1.f / sum;
    __syncthreads();                     // all scratch reads done -> overwrite
    #pragma unroll
    for (int i = 0; i < 8; ++i) {
      const int col = cb + i * 4;
      const float4 q = *(const float4*)&s_bn[col];
      const float4 r = *(const float4*)&s_bn[128 + col];
      const float vx = fmaxf(fmaf(a[i].x * rsv, q.x, r.x), 0.f);
      const float vy = fmaxf(fmaf(a[i].y * rsv, q.y, r.y), 0.f);
      const float vz = fmaxf(fmaf(a[i].z * rsv, q.z, r.z), 0.f);
      const float vw = fmaxf(fmaf(a[i].w * rsv, q.w, r.w), 0.f);
      u32 h0, l0, h1, l1;
      split_pair(vx, vy, h0, l0);
      split_pair(vz, vw, h1, l1);
      const int wi = n * RSP + (cb >> 1) + i * 2;
      *(uint2*)(F + wi)       = make_uint2(h0, h1);
      *(uint2*)(F + PLO + wi) = make_uint2(l0, l1);
    }
  }
  __syncthreads();

  // ======================= GAT layer 1 (1 head) =======================
  mfma_gemm_acc(F, wf + 32768, lw, lane, acc);
  __syncthreads();
  store_acc((float*)F, lw, lane, acc);
  __syncthreads();

  // logits partials: 512 threads -> 4 partials per node
  {
    const int n = t >> 2, c = t & 3;
    const float* row = (const float*)F + n * RSW + c * 32;
    float accs = 0.f, accd = 0.f;
    #pragma unroll
    for (int i = 0; i < 8; ++i) {
      const int d = i * 4;
      const float4 v  = *(const float4*)(row + d);
      const float4 as = *(const float4*)(g1as + c * 32 + d);
      const float4 ad = *(const float4*)(g1ad + c * 32 + d);
      accs += v.x*as.x + v.y*as.y + v.z*as.z + v.w*as.w;
      accd += v.x*ad.x + v.y*ad.y + v.z*ad.z + v.w*ad.w;
    }
    s_es[t] = accs;                      // partials [n*4+c]
    s_ed[t] = accd;
  }
  __syncthreads();
  if (t < 128) {                         // combine -> s_rs[n]=es, s_rs[128+n]=ed
    const float* pe = s_es + t * 4;
    const float* pd = s_ed + t * 4;
    s_rs[t]       = pe[0] + pe[1] + pe[2] + pe[3];
    s_rs[128 + t] = pd[0] + pd[1] + pd[2] + pd[3];
  }
  __syncthreads();

  // aggregation layer 1: thread = (sorted-node, col-quarter); merged pass;
  // epilogue stores RAW f32 (pool is the only consumer)
  {
    const int slot = t & 127, cg = t >> 7;
    const int cb = cg * HSZ;
    const int n = s_perm[slot];
    const float* Ff = (const float*)F;
    const int e0 = s_rp[n], e1 = s_rp[n + 1];
    const float edv = s_rs[128 + n];
    float sum = 0.f;
    float4 a[8];
    #pragma unroll
    for (int i = 0; i < 8; ++i) a[i] = make_float4(0.f, 0.f, 0.f, 0.f);
    for (int e = e0; e < e1; ++e) {
      const int s = s_src[e];
      const float al = __expf(lrelu(s_rs[s] + edv));
      sum += al;
      const float* rp_ = Ff + s * RSW + cb;
      #pragma unroll
      for (int i = 0; i < 8; ++i) {
        const float4 vv = *(const float4*)(rp_ + i * 4);
        a[i].x = fmaf(al, vv.x, a[i].x); a[i].y = fmaf(al, vv.y, a[i].y);
        a[i].z = fmaf(al, vv.z, a[i].z); a[i].w = fmaf(al, vv.w, a[i].w);
      }
    }
    const float rsv = 1.f / sum;
    __syncthreads();                     // all scratch reads done -> overwrite
    #pragma unroll
    for (int i = 0; i < 8; ++i) {
      const int col = cb + i * 4;
      const float4 q = *(const float4*)&s_bn[256 + col];
      const float4 r = *(const float4*)&s_bn[384 + col];
      uint4 p;
      p.x = __float_as_uint(fmaxf(fmaf(a[i].x * rsv, q.x, r.x), 0.f));
      p.y = __float_as_uint(fmaxf(fmaf(a[i].y * rsv, q.y, r.y), 0.f));
      p.z = __float_as_uint(fmaxf(fmaf(a[i].z * rsv, q.z, r.z), 0.f));
      p.w = __float_as_uint(fmaxf(fmaf(a[i].w * rsv, q.w, r.w), 0.f));
      *(uint4*)(F + n * RSW + col) = p;
    }
  }
  __syncthreads();

  // ---- mean pool (raw f32 in F) + MLP head
  {
    const int j = t & 127, q = t >> 7;
    float p = 0.f;
    for (int n = q * 32; n < q * 32 + 32; ++n)
      p += __uint_as_float(F[n * RSW + j]);
    s_es[q * 128 + j] = p;
  }
  __syncthreads();
  if (t < 128) {
    s_ed[t] = (s_es[t] + s_es[t + 128] + s_es[t + 256] + s_es[t + 384])
              * (1.f / 128.f);
  }
  __syncthreads();
  {
    const int j = t & 63, part = t >> 6;
    float a = 0.f;
    #pragma unroll
    for (int k = part * 16; k < part * 16 + 16; ++k)
      a = fmaf(s_ed[k], w1[k * 64 + j], a);
    s_es[part * 64 + j] = a;
  }
  __syncthreads();
  if (t < 64) {
    float a = b1[t];
    #pragma unroll
    for (int p = 0; p < 8; ++p) a += s_es[p * 64 + t];
    a = fmaxf(a, 0.f);
    float v = a * w2[t];
    #pragma unroll
    for (int off = 32; off > 0; off >>= 1) v += __shfl_down(v, off, 64);
    if (t == 0) out[gid] = v + b2[0];
  }
}

extern "C" void kernel_launch(void* const* d_in, const int* in_sizes, int n_in,
                              void* d_out, int out_size, void* d_ws, size_t ws_size,
                              hipStream_t stream)
{
  const float* x    = (const float*)d_in[0];
  const int*   ei   = (const int*)d_in[1];
  const float* w_in = (const float*)d_in[2];
  const float* b_in = (const float*)d_in[3];
  const float* g0w  = (const float*)d_in[4];
  const float* g0as = (const float*)d_in[5];
  const float* g0ad = (const float*)d_in[6];
  const float* g0b  = (const float*)d_in[7];
  const float* bn0g = (const float*)d_in[8];
  const float* bn0b = (const float*)d_in[9];
  const float* bn0m = (const float*)d_in[10];
  const float* bn0v = (const float*)d_in[11];
  const float* g1w  = (const float*)d_in[12];
  const float* g1as = (const float*)d_in[13];
  const float* g1ad = (const float*)d_in[14];
  const float* g1b  = (const float*)d_in[15];
  const float* bn1g = (const float*)d_in[16];
  const float* bn1b = (const float*)d_in[17];
  const float* bn1m = (const float*)d_in[18];
  const float* bn1v = (const float*)d_in[19];
  const float* w1   = (const float*)d_in[20];
  const float* b1   = (const float*)d_in[21];
  const float* w2   = (const float*)d_in[22];
  const float* b2   = (const float*)d_in[23];

  u16* wf   = (u16*)d_ws;                          // 128 KB
  u16* csrS = (u16*)((char*)d_ws + 131072);        // 1152 u16 = 2304 B
  int* csrI = (int*)((char*)d_ws + 131072 + 2304); // rp[129] | perm[128]

  prep_kernel<<<129, 256, 0, stream>>>(g0w, g1w, ei, wf, csrS, csrI);
  gnn_fused_kernel<<<1024, 512, 0, stream>>>(x, w_in, b_in,
      g0as, g0ad, g0b, bn0g, bn0b, bn0m, bn0v,
      g1as, g1ad, g1b, bn1g, bn1b, bn1m, bn1v,
      w1, b1, w2, b2, wf, csrS, csrI, (float*)d_out);
}